// Round 8
// baseline (412.872 us; speedup 1.0000x reference)
//
#include <hip/hip_runtime.h>

#define T_STEPS 256
#define FEAT 16
#define U1 24
#define U2 48
#define ROWB 144
#define RP_STEP 2048
#define RN_STEP (16 * ROWB)
#define RE_STEP 3072
#define RP_OFF 0
#define RN_OFF (RP_OFF + 8 * RP_STEP)
#define RE_OFF (RN_OFF + 8 * RN_STEP)
#define TR_OFF (RE_OFF + 8 * RE_STEP)
#define FLAG_OFF (TR_OFF + 16 * ROWB)
#define LDS_TOTAL (FLAG_OFF + 16)      // 61712 B < 64 KB

typedef short bf16x8 __attribute__((ext_vector_type(8)));
typedef float f32x4 __attribute__((ext_vector_type(4)));

__device__ __forceinline__ unsigned short f2bf(float f) {
    unsigned u = __float_as_uint(f);
    u += 0x7fffu + ((u >> 16) & 1u);   // RNE
    return (unsigned short)(u >> 16);
}

#if defined(__has_builtin)
#if __has_builtin(__builtin_amdgcn_cvt_pk_bf16_f32)
#define HAVE_PKBF16 1
#endif
#endif

__device__ __forceinline__ unsigned pk2(float a, float b) {
#ifdef HAVE_PKBF16
    typedef __bf16 bf2 __attribute__((ext_vector_type(2)));
    union { bf2 v; unsigned u; } cv;
    cv.v = __builtin_amdgcn_cvt_pk_bf16_f32(a, b);       // lo = a, hi = b, RNE
    return cv.u;
#else
    unsigned ua = __float_as_uint(a), ub = __float_as_uint(b);
    ua += 0x7fffu + ((ua >> 16) & 1u);
    ub += 0x7fffu + ((ub >> 16) & 1u);
    return __builtin_amdgcn_perm(ub, ua, 0x07060302);    // [b.hi16 | a.hi16]
#endif
}
__device__ __forceinline__ float fast_tanh(float z) {
    return 1.0f - 2.0f / (1.0f + __expf(2.0f * z));      // robust at +/-inf
}

union FragU { bf16x8 v; unsigned u[4]; };

#define MFMA(A, B, C) __builtin_amdgcn_mfma_f32_16x16x32_bf16((A), (B), (C), 0, 0, 0)

// -------- LDS-flag sync (no s_barrier in the steady state) --------
__device__ __forceinline__ void waitf(volatile unsigned* f, unsigned tgt) {
    while (*f < tgt) __builtin_amdgcn_s_sleep(1);
    asm volatile("" ::: "memory");       // data reads stay after the observed flag
}
__device__ __forceinline__ void postf(volatile unsigned* f, unsigned v, int lane) {
    asm volatile("" ::: "memory");       // data writes stay before the flag write
    if (lane == 0) *f = v;               // same wave's DS queue -> ordered after data
}

__global__ __launch_bounds__(256, 2) void rnn_kernel(
    const float* __restrict__ seq,
    const float* __restrict__ W1, const float* __restrict__ b1,
    const float* __restrict__ Wr1, const float* __restrict__ br1,
    const float* __restrict__ g1, const float* __restrict__ be1,
    const float* __restrict__ W2, const float* __restrict__ b2,
    const float* __restrict__ Wr2, const float* __restrict__ br2,
    const float* __restrict__ g2, const float* __restrict__ be2,
    const float* __restrict__ Wout, const float* __restrict__ bout,
    float* __restrict__ out)
{
    __shared__ __align__(16) unsigned char lds[LDS_TOTAL];
    const int tid = threadIdx.x;
    const int w = tid >> 6, lane = tid & 63, j15 = lane & 15, g = lane >> 4;
    volatile unsigned* flags = (volatile unsigned*)(lds + FLAG_OFF);

    for (int i = tid; i < (16 * ROWB) / 4; i += 256) ((unsigned*)(lds + TR_OFF))[i] = 0u;
    if (tid < 4) flags[tid] = 0u;
    __syncthreads();                                     // only barrier in the kernel

    const f32x4 z4 = {0.f, 0.f, 0.f, 0.f};
    FragU zf; zf.u[0] = zf.u[1] = zf.u[2] = zf.u[3] = 0u;

    if (w == 0) {
        // ======== W0: input stage — Pin = ([W1;b1].Wr1)^T . in_ext + br1 ========
        bf16x8 A1f[2];
        f32x4 Cb1[2];
#pragma unroll
        for (int t = 0; t < 2; ++t) {
            const int m = 16 * t + j15;
            FragU f1;
#pragma unroll
            for (int j = 0; j < 8; ++j) {
                const int k = 8 * g + j;
                float v1 = 0.f;
                if (m < U1 && k <= FEAT) {
                    for (int u = 0; u < U1; ++u) {
                        const float w1e = (k < FEAT) ? W1[k * U1 + u] : b1[u];
                        v1 = fmaf(w1e, Wr1[u * U1 + m], v1);
                    }
                }
                f1.v[j] = (short)f2bf(v1);
            }
            A1f[t] = f1.v;
            f32x4 cb;
#pragma unroll
            for (int r = 0; r < 4; ++r) {
                const int mm = 16 * t + 4 * g + r;
                cb[r] = (mm < U1) ? br1[mm] : 0.f;
            }
            Cb1[t] = cb;
        }
        const unsigned cdw0 = (g == 2) ? 0x00003F80u : 0u;   // input k16 = 1.0
        const bool lo = (g < 2);
        const float* sp = seq + (size_t)(blockIdx.x * 16 + j15) * (T_STEPS * FEAT) + 8 * g;
        const bool ld = (lane < 32);

        float4 ca[4], cb4[4], na[4], nb[4];
        if (ld) {
#pragma unroll
            for (int i = 0; i < 4; ++i) {
                ca[i] = *(const float4*)(sp + i * 16);
                cb4[i] = *(const float4*)(sp + i * 16 + 4);
            }
        }
#pragma unroll 1
        for (int m = 0; m < 64; ++m) {
            const int jn = (m + 1 < 64) ? m + 1 : m;
            if (ld) {
#pragma unroll
                for (int i = 0; i < 4; ++i) {
                    na[i] = *(const float4*)(sp + (4 * jn + i) * 16);
                    nb[i] = *(const float4*)(sp + (4 * jn + i) * 16 + 4);
                }
            }
            if (m >= 2) waitf(&flags[1], (unsigned)(m - 1));   // ring_P backpressure
#pragma unroll
            for (int i = 0; i < 4; ++i) {
                const int s = (4 * m + i) & 7;
                FragU inf;
                const unsigned p0 = pk2(ca[i].x, ca[i].y), p1 = pk2(ca[i].z, ca[i].w);
                const unsigned p2 = pk2(cb4[i].x, cb4[i].y), p3 = pk2(cb4[i].z, cb4[i].w);
                inf.u[0] = lo ? p0 : cdw0;
                inf.u[1] = lo ? p1 : 0u;
                inf.u[2] = lo ? p2 : 0u;
                inf.u[3] = lo ? p3 : 0u;
                const f32x4 PA = MFMA(A1f[0], inf.v, Cb1[0]);
                const f32x4 PB = MFMA(A1f[1], inf.v, Cb1[1]);
                unsigned char* p = lds + RP_OFF + (size_t)s * RP_STEP + (size_t)lane * 16;
                *(f32x4*)(p) = PA;
                *(f32x4*)(p + 1024) = PB;
            }
            postf(&flags[0], (unsigned)(m + 1), lane);
#pragma unroll
            for (int i = 0; i < 4; ++i) { ca[i] = na[i]; cb4[i] = nb[i]; }
        }
    } else if (w == 1) {
        // ======== W1: s1 chain — a = Wr1^T.s1 + Pin; n1 = tanh(a) ========
        bf16x8 A2[2];
#pragma unroll
        for (int t = 0; t < 2; ++t) {
            const int m = 16 * t + j15;
            FragU f2;
#pragma unroll
            for (int j = 0; j < 8; ++j) {
                const int k = 8 * g + j;
                f2.v[j] = (m < U1 && k < U1) ? (short)f2bf(Wr1[k * U1 + m]) : (short)0;
            }
            A2[t] = f2.v;
        }
        bf16x8 s1f = zf.v;
#pragma unroll 1
        for (int m = 0; m < 64; ++m) {
            waitf(&flags[0], (unsigned)(m + 1));
            if (m >= 2) waitf(&flags[2], (unsigned)(m - 1));   // ring_n1 backpressure
#pragma unroll
            for (int i = 0; i < 4; ++i) {
                const int s = (4 * m + i) & 7;
                const unsigned char* p = lds + RP_OFF + (size_t)s * RP_STEP + (size_t)lane * 16;
                const f32x4 C0 = *(const f32x4*)(p);
                const f32x4 C1 = *(const f32x4*)(p + 1024);
                const f32x4 a0 = MFMA(A2[0], s1f, C0);
                const f32x4 a1 = MFMA(A2[1], s1f, C1);
                float n1a[4], n1b[4];
#pragma unroll
                for (int r = 0; r < 4; ++r) { n1a[r] = fast_tanh(a0[r]); n1b[r] = fast_tanh(a1[r]); }
                unsigned char* rp = lds + RN_OFF + (size_t)s * RN_STEP + (size_t)j15 * ROWB;
                *(uint2*)(rp + 8 * g)      = make_uint2(pk2(n1a[0], n1a[1]), pk2(n1a[2], n1a[3]));
                *(uint2*)(rp + 32 + 8 * g) = make_uint2(pk2(n1b[0], n1b[1]), pk2(n1b[2], n1b[3]));
                s1f = *(const bf16x8*)(rp + 16 * g);           // own readback (in-order DS)
            }
            postf(&flags[1], (unsigned)(m + 1), lane);
        }
    } else if (w == 2) {
        // ======== W2: stats + Q + E = rs.Q - rs.mu.q1 + q2 ========
        bf16x8 AQ[3];
#pragma unroll
        for (int t = 0; t < 3; ++t) {
            const int m = 16 * t + j15;
            FragU fq;
#pragma unroll
            for (int j = 0; j < 8; ++j) {
                const int k = 8 * g + j;
                float vq = 0.f;
                if (k < U1) {
                    float s = 0.f;
                    for (int u = 0; u < U2; ++u) s = fmaf(W2[k * U2 + u], Wr2[u * U2 + m], s);
                    vq = g1[k] * s;
                }
                fq.v[j] = (short)f2bf(vq);
            }
            AQ[t] = fq.v;
        }
        float q1C[12], q2C[12];
        {
            float cv[U2], dv[U2];
            for (int u = 0; u < U2; ++u) {
                float cc = 0.f, dd = b2[u];
                for (int k = 0; k < U1; ++k) {
                    const float w2 = W2[k * U2 + u];
                    cc = fmaf(g1[k], w2, cc);
                    dd = fmaf(be1[k], w2, dd);
                }
                cv[u] = cc; dv[u] = dd;
            }
#pragma unroll
            for (int i = 0; i < 12; ++i) {
                const int m = 16 * (i >> 2) + 4 * g + (i & 3);
                float a1 = 0.f, a2 = br2[m];
                for (int u = 0; u < U2; ++u) {
                    const float wr = Wr2[u * U2 + m];
                    a1 = fmaf(cv[u], wr, a1);
                    a2 = fmaf(dv[u], wr, a2);
                }
                q1C[i] = a1; q2C[i] = a2;
            }
        }
#pragma unroll 1
        for (int m = 0; m < 64; ++m) {
            waitf(&flags[1], (unsigned)(m + 1));
            if (m >= 2) waitf(&flags[3], (unsigned)(m - 1));   // ring_E backpressure
#pragma unroll
            for (int i = 0; i < 4; ++i) {
                const int s = (4 * m + i) & 7;
                FragU nu;
                nu.v = *(const bf16x8*)(lds + RN_OFF + (size_t)s * RN_STEP + (size_t)j15 * ROWB + 16 * g);
                // per-batch stats from the 8 local bf16 (g-lanes reduce via shfl)
                float sm = 0.f, sq = 0.f;
#pragma unroll
                for (int d = 0; d < 4; ++d) {
                    const float flo = __uint_as_float(nu.u[d] << 16);
                    const float fhi = __uint_as_float(nu.u[d] & 0xffff0000u);
                    sm += flo + fhi;
                    sq = fmaf(flo, flo, sq);
                    sq = fmaf(fhi, fhi, sq);
                }
                sm += __shfl_xor(sm, 16, 64); sq += __shfl_xor(sq, 16, 64);
                sm += __shfl_xor(sm, 32, 64); sq += __shfl_xor(sq, 32, 64);
                const float mu = sm * (1.f / U1);
                const float rs = rsqrtf(sq * (1.f / U1) - mu * mu + 1e-3f);
                const float rsmu = rs * mu;

                const f32x4 Q0 = MFMA(AQ[0], nu.v, z4);
                const f32x4 Q1 = MFMA(AQ[1], nu.v, z4);
                const f32x4 Q2 = MFMA(AQ[2], nu.v, z4);
                f32x4 E0, E1, E2;
#pragma unroll
                for (int r = 0; r < 4; ++r) {
                    E0[r] = fmaf(rs, Q0[r], fmaf(-rsmu, q1C[r],     q2C[r]));
                    E1[r] = fmaf(rs, Q1[r], fmaf(-rsmu, q1C[4 + r], q2C[4 + r]));
                    E2[r] = fmaf(rs, Q2[r], fmaf(-rsmu, q1C[8 + r], q2C[8 + r]));
                }
                unsigned char* p = lds + RE_OFF + (size_t)s * RE_STEP + (size_t)lane * 16;
                *(f32x4*)(p) = E0;
                *(f32x4*)(p + 1024) = E1;
                *(f32x4*)(p + 2048) = E2;
            }
            postf(&flags[2], (unsigned)(m + 1), lane);
        }
    } else {
        // ======== W3: s2 chain — e = Wr2^T.s2 + E; s2 = tanh(e) ========
        bf16x8 A4[3][2];
#pragma unroll
        for (int t = 0; t < 3; ++t) {
            const int m = 16 * t + j15;
            FragU f4a, f4b;
#pragma unroll
            for (int j = 0; j < 8; ++j) {
                const int k = 8 * g + j;
                const int kb = 32 + k;
                f4a.v[j] = (short)f2bf(Wr2[k * U2 + m]);
                f4b.v[j] = (kb < U2) ? (short)f2bf(Wr2[kb * U2 + m]) : (short)0;
            }
            A4[t][0] = f4a.v; A4[t][1] = f4b.v;
        }
        unsigned char* const yrow = lds + TR_OFF + (size_t)j15 * ROWB;
        f32x4 s2c[3] = {z4, z4, z4};
        bf16x8 s2f0 = zf.v, s2f1 = zf.v;
#pragma unroll 1
        for (int m = 0; m < 64; ++m) {
            waitf(&flags[2], (unsigned)(m + 1));
#pragma unroll
            for (int i = 0; i < 4; ++i) {
                const int s = (4 * m + i) & 7;
                const unsigned char* p = lds + RE_OFF + (size_t)s * RE_STEP + (size_t)lane * 16;
                const f32x4 E0 = *(const f32x4*)(p);
                const f32x4 E1 = *(const f32x4*)(p + 1024);
                const f32x4 E2 = *(const f32x4*)(p + 2048);
                f32x4 e0 = MFMA(A4[0][0], s2f0, E0);
                f32x4 e1 = MFMA(A4[1][0], s2f0, E1);
                f32x4 e2 = MFMA(A4[2][0], s2f0, E2);
                e0 = MFMA(A4[0][1], s2f1, e0);
                e1 = MFMA(A4[1][1], s2f1, e1);
                e2 = MFMA(A4[2][1], s2f1, e2);
#pragma unroll
                for (int r = 0; r < 4; ++r) {
                    s2c[0][r] = fast_tanh(e0[r]);
                    s2c[1][r] = fast_tanh(e1[r]);
                    s2c[2][r] = fast_tanh(e2[r]);
                }
                *(uint2*)(yrow + 8 * g)      = make_uint2(pk2(s2c[0][0], s2c[0][1]), pk2(s2c[0][2], s2c[0][3]));
                *(uint2*)(yrow + 32 + 8 * g) = make_uint2(pk2(s2c[1][0], s2c[1][1]), pk2(s2c[1][2], s2c[1][3]));
                *(uint2*)(yrow + 64 + 8 * g) = make_uint2(pk2(s2c[2][0], s2c[2][1]), pk2(s2c[2][2], s2c[2][3]));
                s2f0 = *(const bf16x8*)(yrow + 16 * g);
                s2f1 = *(const bf16x8*)(yrow + 64 + 16 * g);
            }
            postf(&flags[3], (unsigned)(m + 1), lane);
        }

        // ---- epilogue: out = sigmoid(LN(s2) @ Wout + bout) ----
        float g2r[12], be2r[12], wor[12];
#pragma unroll
        for (int r = 0; r < 12; ++r) {
            const int n = 16 * (r >> 2) + 4 * g + (r & 3);
            g2r[r] = g2[n]; be2r[r] = be2[n]; wor[r] = Wout[n];
        }
        float sm = 0.f, sq = 0.f;
#pragma unroll
        for (int tt = 0; tt < 3; ++tt)
#pragma unroll
            for (int r = 0; r < 4; ++r) { const float v = s2c[tt][r]; sm += v; sq += v * v; }
        sm += __shfl_xor(sm, 16, 64); sq += __shfl_xor(sq, 16, 64);
        sm += __shfl_xor(sm, 32, 64); sq += __shfl_xor(sq, 32, 64);
        const float mu = sm * (1.f / U2);
        const float var = sq * (1.f / U2) - mu * mu;
        const float rs = rsqrtf(var + 1e-3f);
        float p = 0.f;
#pragma unroll
        for (int tt = 0; tt < 3; ++tt)
#pragma unroll
            for (int r = 0; r < 4; ++r)
                p += ((s2c[tt][r] - mu) * rs * g2r[4 * tt + r] + be2r[4 * tt + r]) * wor[4 * tt + r];
        p += __shfl_xor(p, 16, 64);
        p += __shfl_xor(p, 32, 64);
        if (lane < 16) {
            const float z = p + bout[0];
            out[blockIdx.x * 16 + lane] = 1.0f / (1.0f + __expf(-z));
        }
    }
}

extern "C" void kernel_launch(void* const* d_in, const int* in_sizes, int n_in,
                              void* d_out, int out_size, void* d_ws, size_t ws_size,
                              hipStream_t stream) {
    const float* seq  = (const float*)d_in[0];
    const float* W1   = (const float*)d_in[1];
    const float* b1   = (const float*)d_in[2];
    const float* Wr1  = (const float*)d_in[3];
    const float* br1  = (const float*)d_in[4];
    const float* g1   = (const float*)d_in[5];
    const float* be1  = (const float*)d_in[6];
    const float* W2   = (const float*)d_in[7];
    const float* b2   = (const float*)d_in[8];
    const float* Wr2  = (const float*)d_in[9];
    const float* br2  = (const float*)d_in[10];
    const float* g2   = (const float*)d_in[11];
    const float* be2  = (const float*)d_in[12];
    const float* Wout = (const float*)d_in[13];
    const float* bout = (const float*)d_in[14];
    float* out = (float*)d_out;

    const int B = in_sizes[0] / (T_STEPS * FEAT);   // 8192
    const int grid = B / 16;                        // 512 blocks x 4 waves
    rnn_kernel<<<grid, 256, 0, stream>>>(seq, W1, b1, Wr1, br1, g1, be1,
                                         W2, b2, Wr2, br2, g2, be2, Wout, bout, out);
}

// Round 9
// 390.120 us; speedup vs baseline: 1.0583x; 1.0583x over previous
//
#include <hip/hip_runtime.h>

#define T_STEPS 256
#define FEAT 16
#define U1 24
#define U2 48
#define ROWB 144
#define SLOT_ROWS (16 * ROWB)          // 2304 B per slot (rows)
#define SUMS_BASE (8 * SLOT_ROWS)      // 18432
#define RING_BYTES (SUMS_BASE + 8 * 128)

typedef short bf16x8 __attribute__((ext_vector_type(8)));
typedef float f32x4 __attribute__((ext_vector_type(4)));

__device__ __forceinline__ unsigned short f2bf(float f) {
    unsigned u = __float_as_uint(f);
    u += 0x7fffu + ((u >> 16) & 1u);   // RNE
    return (unsigned short)(u >> 16);
}

#if defined(__has_builtin)
#if __has_builtin(__builtin_amdgcn_cvt_pk_bf16_f32)
#define HAVE_PKBF16 1
#endif
#endif

__device__ __forceinline__ unsigned pk2(float a, float b) {
#ifdef HAVE_PKBF16
    typedef __bf16 bf2 __attribute__((ext_vector_type(2)));
    union { bf2 v; unsigned u; } cv;
    cv.v = __builtin_amdgcn_cvt_pk_bf16_f32(a, b);       // lo = a, hi = b, RNE
    return cv.u;
#else
    unsigned ua = __float_as_uint(a), ub = __float_as_uint(b);
    ua += 0x7fffu + ((ua >> 16) & 1u);
    ub += 0x7fffu + ((ub >> 16) & 1u);
    return __builtin_amdgcn_perm(ub, ua, 0x07060302);    // [b.hi16 | a.hi16]
#endif
}
__device__ __forceinline__ float bfr(float x) {          // f32 -> bf16 -> f32
    return __uint_as_float(((unsigned)f2bf(x)) << 16);
}

// ---- fast transcendentals: no -ffast-math in harness, so 1/x would expand to
// the ~12-instr IEEE div sequence. Use HW approx ops directly (~1 ulp). ----
__device__ __forceinline__ float rcp_fast(float x) {
#if __has_builtin(__builtin_amdgcn_rcpf)
    return __builtin_amdgcn_rcpf(x);
#else
    return 1.0f / x;
#endif
}
__device__ __forceinline__ float exp2_fast(float x) {
#if __has_builtin(__builtin_amdgcn_exp2f)
    return __builtin_amdgcn_exp2f(x);
#else
    return exp2f(x);
#endif
}
__device__ __forceinline__ float rsq_fast(float x) {
#if __has_builtin(__builtin_amdgcn_rsqf)
    return __builtin_amdgcn_rsqf(x);
#else
    return rsqrtf(x);
#endif
}
__device__ __forceinline__ float fast_tanh(float z) {
    // 1 - 2*rcp(1 + 2^(2z/ln2)); z->+inf: rcp(inf)=0 -> 1; z->-inf: rcp(1)=1 -> -1
    const float e = exp2_fast(2.885390081777927f * z);
    return fmaf(-2.0f, rcp_fast(1.0f + e), 1.0f);
}

union FragU { bf16x8 v; unsigned u[4]; };

#define MFMA(A, B, C) __builtin_amdgcn_mfma_f32_16x16x32_bf16((A), (B), (C), 0, 0, 0)

// lgkm-only barrier (0xC07F = vmcnt(63) expcnt(7) lgkmcnt(0)):
// input-prefetch global loads stay in flight across the barrier.
__device__ __forceinline__ void bar_sync() {
    asm volatile("" ::: "memory");
    __builtin_amdgcn_s_waitcnt(0xC07F);
    __builtin_amdgcn_s_barrier();
    asm volatile("" ::: "memory");
}

__global__ __launch_bounds__(128) void rnn_kernel(
    const float* __restrict__ seq,
    const float* __restrict__ W1, const float* __restrict__ b1,
    const float* __restrict__ Wr1, const float* __restrict__ br1,
    const float* __restrict__ g1, const float* __restrict__ be1,
    const float* __restrict__ W2, const float* __restrict__ b2,
    const float* __restrict__ Wr2, const float* __restrict__ br2,
    const float* __restrict__ g2, const float* __restrict__ be2,
    const float* __restrict__ Wout, const float* __restrict__ bout,
    float* __restrict__ out)
{
    __shared__ __align__(16) unsigned char ring[RING_BYTES];   // n1 rows + (mu,rs)
    __shared__ __align__(16) unsigned char tr0[16 * ROWB];     // producer x RT
    __shared__ __align__(16) unsigned char tr1[16 * ROWB];     // consumer y RT

    const int tid = threadIdx.x;
    const int w = tid >> 6;              // 0 = layer-1 producer, 1 = layer-2 consumer
    const int lane = tid & 63;
    const int j15 = lane & 15;
    const int g = lane >> 4;
    const f32x4 z4 = {0.f, 0.f, 0.f, 0.f};

    if (w == 0) {
        // ================= PRODUCER: layer 1 (s1 chain) =================
        bf16x8 A1[2], A2[2];
#pragma unroll
        for (int t = 0; t < 2; ++t) {
            const int m = 16 * t + j15;
            FragU f1, f2;
#pragma unroll
            for (int j = 0; j < 8; ++j) {
                const int k = 8 * g + j;
                float v1 = 0.f, v2 = 0.f;
                if (m < U1) {
                    if (k < FEAT) v1 = W1[k * U1 + m];
                    else if (k == FEAT) v1 = b1[m];      // bias col (input k16 == 1)
                    if (k < U1) v2 = Wr1[k * U1 + m];
                    else if (k == U1) v2 = br1[m];       // bias col (x24 == 1)
                } else if (m == U1 && k == FEAT) {
                    v1 = 1.f;                            // keeps x24 = 1 each step
                }
                f1.v[j] = (short)f2bf(v1);
                f2.v[j] = (short)f2bf(v2);
            }
            A1[t] = f1.v; A2[t] = f2.v;
        }
        const unsigned cdw0 = (g == 2) ? 0x00003F80u : 0u;   // input k16 = 1.0
        const bool lo = (g < 2);
        unsigned char* const xw = tr0 + (size_t)j15 * ROWB + 8 * g;
        const unsigned char* const xr = tr0 + (size_t)j15 * ROWB + 16 * g;
        unsigned char* const nw = ring + (size_t)j15 * ROWB + 8 * g;
        float2* const sw = (float2*)(ring + SUMS_BASE + 8 * j15);

        const float* sp = seq + (size_t)(blockIdx.x * 16 + j15) * (T_STEPS * FEAT) + 8 * g;
        const bool ld = (lane < 32);

        float4 cA[4], cB[4], nA[4], nB[4];
        if (!ld) {   // non-loader lanes keep zeros forever (NaN-safe MFMA pads)
#pragma unroll
            for (int i = 0; i < 4; ++i) {
                cA[i] = make_float4(0.f, 0.f, 0.f, 0.f); cB[i] = cA[i];
                nA[i] = cA[i]; nB[i] = cA[i];
            }
        }
        auto load4 = [&](float4* A, float4* Bv, int gidx) {
            if (ld) {
                const float* q = sp + (size_t)gidx * 64;
#pragma unroll
                for (int i = 0; i < 4; ++i) {
                    A[i] = *(const float4*)(q + 16 * i);
                    Bv[i] = *(const float4*)(q + 16 * i + 4);
                }
            }
        };

        f32x4 s1[2] = {z4, z4};

        auto pstep = [&](const int s, const float4 ca, const float4 cb) {
            FragU inf;
            inf.u[0] = lo ? pk2(ca.x, ca.y) : cdw0;   // k16=1.0 for g==2; pads 0
            inf.u[1] = pk2(ca.z, ca.w);               // zero-filled regs in pad lanes
            inf.u[2] = pk2(cb.x, cb.y);
            inf.u[3] = pk2(cb.z, cb.w);

            // GEMM1: x^T = [W1^T|b1].in^T + s1
            const f32x4 x0 = MFMA(A1[0], inf.v, s1[0]);
            const f32x4 x1 = MFMA(A1[1], inf.v, s1[1]);

            // transpose x through private scratch (static addresses)
            *(uint2*)(xw)      = make_uint2(pk2(x0[0], x0[1]), pk2(x0[2], x0[3]));
            *(uint2*)(xw + 32) = make_uint2(pk2(x1[0], x1[1]), pk2(x1[2], x1[3]));
            const bf16x8 xf = *(const bf16x8*)(xr);

            // GEMM2: ns1 = tanh([Wr1^T|br1].x^T)
            const f32x4 d0 = MFMA(A2[0], xf, z4);
            const f32x4 d1 = MFMA(A2[1], xf, z4);
            float n1a[4], n1b[4];
#pragma unroll
            for (int r = 0; r < 4; ++r) {
                n1a[r] = fast_tanh(d0[r]); n1b[r] = fast_tanh(d1[r]);
                s1[0][r] = n1a[r];         s1[1][r] = n1b[r];
            }
            // ring write: slot offset is a compile-time immediate
            *(uint2*)(nw + s * SLOT_ROWS)      = make_uint2(pk2(n1a[0], n1a[1]), pk2(n1a[2], n1a[3]));
            *(uint2*)(nw + s * SLOT_ROWS + 32) = make_uint2(pk2(n1b[0], n1b[1]), pk2(n1b[2], n1b[3]));

            // off-chain stats -> (mu, rs)
            float sm = 0.f, sq = 0.f;
#pragma unroll
            for (int r = 0; r < 4; ++r) {
                sm += n1a[r] + n1b[r];
                sq = fmaf(n1a[r], n1a[r], sq);
                sq = fmaf(n1b[r], n1b[r], sq);
            }
            sm += __shfl_xor(sm, 16, 64); sq += __shfl_xor(sq, 16, 64);
            sm += __shfl_xor(sm, 32, 64); sq += __shfl_xor(sq, 32, 64);
            const float mu = sm * (1.f / U1);
            const float rs = rsq_fast(sq * (1.f / U1) - mu * mu + 1e-3f);
            if (lane < 16) sw[s * 16] = make_float2(mu, rs);
        };

        load4(cA, cB, 0);
        load4(nA, nB, 1);
#pragma unroll 1
        for (int j = 0; j < 32; ++j) {
            pstep(0, cA[0], cB[0]); pstep(1, cA[1], cB[1]);
            pstep(2, cA[2], cB[2]); pstep(3, cA[3], cB[3]);
            load4(cA, cB, (2 * j + 2 < 64) ? 2 * j + 2 : 63);
            bar_sync();
            pstep(4, nA[0], nB[0]); pstep(5, nA[1], nB[1]);
            pstep(6, nA[2], nB[2]); pstep(7, nA[3], nB[3]);
            load4(nA, nB, (2 * j + 3 < 64) ? 2 * j + 3 : 63);
            bar_sync();
        }
        bar_sync();                                      // balance consumer's initial
    } else {
        // ================= CONSUMER: layer 2 (s2 chain) =================
        for (int i = lane; i < 16 * ROWB / 4; i += 64) ((unsigned*)tr1)[i] = 0u;
        if (lane < 16) *(unsigned short*)(tr1 + lane * ROWB + 96) = 0x3F80;  // k48 = 1.0

        bf16x8 A3a[3], A4[3][2];
#pragma unroll
        for (int t = 0; t < 3; ++t) {
            const int m = 16 * t + j15;
            FragU f3, f4a, f4b;
#pragma unroll
            for (int j = 0; j < 8; ++j) {
                const int k = 8 * g + j;                 // 0..31
                const float v3 = (k < U1) ? g1[k] * W2[k * U2 + m] : 0.f;
                const int kb = 32 + k;                   // 32..63
                const float va = Wr2[k * U2 + m];
                const float vb = (kb < U2) ? Wr2[kb * U2 + m] : (kb == U2 ? br2[m] : 0.f);
                f3.v[j] = (short)f2bf(v3);
                f4a.v[j] = (short)f2bf(va);
                f4b.v[j] = (short)f2bf(vb);
            }
            A3a[t] = f3.v; A4[t][0] = f4a.v; A4[t][1] = f4b.v;
        }
        float cC[12], dC[12];
#pragma unroll
        for (int i = 0; i < 12; ++i) {
            const int m = 16 * (i >> 2) + 4 * g + (i & 3);
            float cc = 0.f, dd = b2[m];
            for (int k = 0; k < U1; ++k) {
                cc += bfr(g1[k] * W2[k * U2 + m]);       // match matmul quantization
                dd += be1[k] * W2[k * U2 + m];
            }
            cC[i] = cc; dC[i] = dd;
        }
        const unsigned char* const nf = ring + (size_t)j15 * ROWB + 16 * g;
        const float2* const msb = (const float2*)(ring + SUMS_BASE + 8 * j15);
        unsigned char* const yw = tr1 + (size_t)j15 * ROWB + 8 * g;
        const unsigned char* const yr = tr1 + (size_t)j15 * ROWB + 16 * g;

        f32x4 s2[3] = {z4, z4, z4};

        auto cstep = [&](const int s) {
            const bf16x8 hf0 = *(const bf16x8*)(nf + s * SLOT_ROWS);
            const float2 ms = msb[s * 16];

            // GEMM3 P-tiles (gamma-folded W2^T . n1^T)
            const f32x4 P0 = MFMA(A3a[0], hf0, z4);
            const f32x4 P1 = MFMA(A3a[1], hf0, z4);
            const f32x4 P2 = MFMA(A3a[2], hf0, z4);
            const float mu = ms.x, rs = ms.y;

            // y = rs*(P - mu*c) + (d + s2)
            float y[12];
#pragma unroll
            for (int r = 0; r < 4; ++r) {
                y[r]     = fmaf(rs, fmaf(-mu, cC[r],     P0[r]), dC[r]     + s2[0][r]);
                y[4 + r] = fmaf(rs, fmaf(-mu, cC[4 + r], P1[r]), dC[4 + r] + s2[1][r]);
                y[8 + r] = fmaf(rs, fmaf(-mu, cC[8 + r], P2[r]), dC[8 + r] + s2[2][r]);
            }

            // transpose y (k48 slot = persistent 1.0)
            *(uint2*)(yw)      = make_uint2(pk2(y[0], y[1]), pk2(y[2], y[3]));
            *(uint2*)(yw + 32) = make_uint2(pk2(y[4], y[5]), pk2(y[6], y[7]));
            *(uint2*)(yw + 64) = make_uint2(pk2(y[8], y[9]), pk2(y[10], y[11]));
            const bf16x8 yf0 = *(const bf16x8*)(yr);
            const bf16x8 yf1 = *(const bf16x8*)(yr + 64);

            // GEMM4: s2 = tanh([Wr2^T|br2].y^T)
#pragma unroll
            for (int t3 = 0; t3 < 3; ++t3) {
                f32x4 e = MFMA(A4[t3][0], yf0, z4);
                e = MFMA(A4[t3][1], yf1, e);
#pragma unroll
                for (int r = 0; r < 4; ++r) s2[t3][r] = fast_tanh(e[r]);
            }
        };

        bar_sync();                                      // producer group 0 done
#pragma unroll 1
        for (int j = 0; j < 32; ++j) {
            cstep(0); cstep(1); cstep(2); cstep(3);
            bar_sync();
            cstep(4); cstep(5); cstep(6); cstep(7);
            bar_sync();
        }

        // ---- epilogue: out = sigmoid(LN(s2) @ Wout + bout) ----
        float g2r[12], be2r[12], wor[12];
#pragma unroll
        for (int r = 0; r < 12; ++r) {
            const int n = 16 * (r >> 2) + 4 * g + (r & 3);
            g2r[r] = g2[n]; be2r[r] = be2[n]; wor[r] = Wout[n];
        }
        float sm = 0.f, sq = 0.f;
#pragma unroll
        for (int tt = 0; tt < 3; ++tt)
#pragma unroll
            for (int r = 0; r < 4; ++r) { const float v = s2[tt][r]; sm += v; sq += v * v; }
        sm += __shfl_xor(sm, 16, 64); sq += __shfl_xor(sq, 16, 64);
        sm += __shfl_xor(sm, 32, 64); sq += __shfl_xor(sq, 32, 64);
        const float mu = sm * (1.f / U2);
        const float var = sq * (1.f / U2) - mu * mu;
        const float rs = rsq_fast(var + 1e-3f);
        float p = 0.f;
#pragma unroll
        for (int tt = 0; tt < 3; ++tt)
#pragma unroll
            for (int r = 0; r < 4; ++r)
                p += ((s2[tt][r] - mu) * rs * g2r[4 * tt + r] + be2r[4 * tt + r]) * wor[4 * tt + r];
        p += __shfl_xor(p, 16, 64);
        p += __shfl_xor(p, 32, 64);
        if (lane < 16) {
            const float z = p + bout[0];
            out[blockIdx.x * 16 + lane] = rcp_fast(1.0f + exp2_fast(-1.4426950408889634f * z));
        }
    }
}

extern "C" void kernel_launch(void* const* d_in, const int* in_sizes, int n_in,
                              void* d_out, int out_size, void* d_ws, size_t ws_size,
                              hipStream_t stream) {
    const float* seq  = (const float*)d_in[0];
    const float* W1   = (const float*)d_in[1];
    const float* b1   = (const float*)d_in[2];
    const float* Wr1  = (const float*)d_in[3];
    const float* br1  = (const float*)d_in[4];
    const float* g1   = (const float*)d_in[5];
    const float* be1  = (const float*)d_in[6];
    const float* W2   = (const float*)d_in[7];
    const float* b2   = (const float*)d_in[8];
    const float* Wr2  = (const float*)d_in[9];
    const float* br2  = (const float*)d_in[10];
    const float* g2   = (const float*)d_in[11];
    const float* be2  = (const float*)d_in[12];
    const float* Wout = (const float*)d_in[13];
    const float* bout = (const float*)d_in[14];
    float* out = (float*)d_out;

    const int B = in_sizes[0] / (T_STEPS * FEAT);   // 8192
    const int grid = B / 16;                        // 512 blocks x 2 waves
    rnn_kernel<<<grid, 128, 0, stream>>>(seq, W1, b1, Wr1, br1, g1, be1,
                                         W2, b2, Wr2, br2, g2, be2, Wout, bout, out);
}

// Round 10
// 371.164 us; speedup vs baseline: 1.1124x; 1.0511x over previous
//
#include <hip/hip_runtime.h>

#define T_STEPS 256
#define FEAT 16
#define U1 24
#define U2 48
#define SLOTS 16                       // barrier every 8 steps -> 2x8 slot skew
#define ROWB 144                       // ring row stride (empirically OK conflicts)
#define SLOT_B (16 * ROWB + 128)       // 16 rows + 16 x float2 (mu-slot unused pad)
#define SUMS_OFF (16 * ROWB)

typedef short bf16x8 __attribute__((ext_vector_type(8)));
typedef float f32x4 __attribute__((ext_vector_type(4)));

__device__ __forceinline__ unsigned short f2bf(float f) {
    unsigned u = __float_as_uint(f);
    u += 0x7fffu + ((u >> 16) & 1u);   // RNE
    return (unsigned short)(u >> 16);
}

#if defined(__has_builtin)
#if __has_builtin(__builtin_amdgcn_cvt_pk_bf16_f32)
#define HAVE_PKBF16 1
#endif
#endif

__device__ __forceinline__ unsigned pk2(float a, float b) {
#ifdef HAVE_PKBF16
    typedef __bf16 bf2 __attribute__((ext_vector_type(2)));
    union { bf2 v; unsigned u; } cv;
    cv.v = __builtin_amdgcn_cvt_pk_bf16_f32(a, b);       // lo = a, hi = b, RNE
    return cv.u;
#else
    unsigned ua = __float_as_uint(a), ub = __float_as_uint(b);
    ua += 0x7fffu + ((ua >> 16) & 1u);
    ub += 0x7fffu + ((ub >> 16) & 1u);
    return __builtin_amdgcn_perm(ub, ua, 0x07060302);    // [b.hi16 | a.hi16]
#endif
}
__device__ __forceinline__ float bfr(float x) {          // f32 -> bf16 -> f32
    return __uint_as_float(((unsigned)f2bf(x)) << 16);
}

// ---- fast transcendentals (harness compiles w/o -ffast-math; avoid IEEE div) ----
__device__ __forceinline__ float rcp_fast(float x) {
#if __has_builtin(__builtin_amdgcn_rcpf)
    return __builtin_amdgcn_rcpf(x);
#else
    return 1.0f / x;
#endif
}
__device__ __forceinline__ float exp2_fast(float x) {
#if __has_builtin(__builtin_amdgcn_exp2f)
    return __builtin_amdgcn_exp2f(x);
#else
    return exp2f(x);
#endif
}
__device__ __forceinline__ float rsq_fast(float x) {
#if __has_builtin(__builtin_amdgcn_rsqf)
    return __builtin_amdgcn_rsqf(x);
#else
    return rsqrtf(x);
#endif
}
__device__ __forceinline__ float fast_tanh(float z) {
    // 1 - 2*rcp(1 + 2^(2z/ln2)); +inf -> 1, -inf -> -1
    const float e = exp2_fast(2.885390081777927f * z);
    return fmaf(-2.0f, rcp_fast(1.0f + e), 1.0f);
}

union FragU { bf16x8 v; unsigned u[4]; };

#define MFMA(A, B, C) __builtin_amdgcn_mfma_f32_16x16x32_bf16((A), (B), (C), 0, 0, 0)

// lgkm-only barrier (0xC07F = vmcnt(63) expcnt(7) lgkmcnt(0)):
// input-prefetch global loads stay in flight across the barrier.
__device__ __forceinline__ void bar_sync() {
    asm volatile("" ::: "memory");
    __builtin_amdgcn_s_waitcnt(0xC07F);
    __builtin_amdgcn_s_barrier();
    asm volatile("" ::: "memory");
}

__global__ __launch_bounds__(128) void rnn_kernel(
    const float* __restrict__ seq,
    const float* __restrict__ W1, const float* __restrict__ b1,
    const float* __restrict__ Wr1, const float* __restrict__ br1,
    const float* __restrict__ g1, const float* __restrict__ be1,
    const float* __restrict__ W2, const float* __restrict__ b2,
    const float* __restrict__ Wr2, const float* __restrict__ br2,
    const float* __restrict__ g2, const float* __restrict__ be2,
    const float* __restrict__ Wout, const float* __restrict__ bout,
    float* __restrict__ out)
{
    __shared__ __align__(16) unsigned char ring[SLOTS * SLOT_B];   // n1|n1^2 rows
    __shared__ __align__(16) unsigned char tr0[16 * ROWB];         // producer x RT
    __shared__ __align__(16) unsigned char tr1[16 * ROWB];         // consumer y RT

    const int tid = threadIdx.x;
    const int w = tid >> 6;              // 0 = layer-1 producer, 1 = layer-2 consumer
    const int lane = tid & 63;
    const int j15 = lane & 15;
    const int g = lane >> 4;
    const f32x4 z4 = {0.f, 0.f, 0.f, 0.f};

    if (w == 0) {
        // ================= PRODUCER: layer 1 (s1 chain) =================
        bf16x8 A1[2], A2[2];
#pragma unroll
        for (int t = 0; t < 2; ++t) {
            const int m = 16 * t + j15;
            FragU f1, f2;
#pragma unroll
            for (int j = 0; j < 8; ++j) {
                const int k = 8 * g + j;
                float v1 = 0.f, v2 = 0.f;
                if (m < U1) {
                    if (k < FEAT) v1 = W1[k * U1 + m];
                    else if (k == FEAT) v1 = b1[m];      // bias col (input k16 == 1)
                    if (k < U1) v2 = Wr1[k * U1 + m];
                    else if (k == U1) v2 = br1[m];       // bias col (x24 == 1)
                } else if (m == U1 && k == FEAT) {
                    v1 = 1.f;                            // keeps x24 = 1 each step
                }
                f1.v[j] = (short)f2bf(v1);
                f2.v[j] = (short)f2bf(v2);
            }
            A1[t] = f1.v; A2[t] = f2.v;
        }
        const unsigned cdw0 = (g == 2) ? 0x00003F80u : 0u;   // input k16 = 1.0
        const bool lo = (g < 2);

        const float* sp = seq + (size_t)(blockIdx.x * 16 + j15) * (T_STEPS * FEAT) + 8 * g;
        const bool ld = (lane < 32);

        f32x4 s1[2] = {z4, z4};

        auto pstep = [&](int t, const float4 ca, const float4 cb) {
            FragU inf;
            const unsigned p0 = pk2(ca.x, ca.y), p1 = pk2(ca.z, ca.w);
            const unsigned p2 = pk2(cb.x, cb.y), p3 = pk2(cb.z, cb.w);
            inf.u[0] = lo ? p0 : cdw0;
            inf.u[1] = lo ? p1 : 0u;
            inf.u[2] = lo ? p2 : 0u;
            inf.u[3] = lo ? p3 : 0u;

            // GEMM1: x^T = [W1^T|b1].in^T + s1  (C-layout)
            const f32x4 x0 = MFMA(A1[0], inf.v, s1[0]);
            const f32x4 x1 = MFMA(A1[1], inf.v, s1[1]);

            // transpose x through private scratch
            unsigned char* xrow = tr0 + (size_t)j15 * ROWB;
            *(uint2*)(xrow + 8 * g)      = make_uint2(pk2(x0[0], x0[1]), pk2(x0[2], x0[3]));
            *(uint2*)(xrow + 32 + 8 * g) = make_uint2(pk2(x1[0], x1[1]), pk2(x1[2], x1[3]));
            const bf16x8 xf = *(const bf16x8*)(xrow + 16 * g);

            // GEMM2: ns1 = tanh([Wr1^T|br1].x^T)
            const f32x4 d0 = MFMA(A2[0], xf, z4);
            const f32x4 d1 = MFMA(A2[1], xf, z4);
            float n1a[4], n1b[4], qa[4], qb[4];
#pragma unroll
            for (int r = 0; r < 4; ++r) {
                n1a[r] = fast_tanh(d0[r]); n1b[r] = fast_tanh(d1[r]);
                qa[r] = n1a[r] * n1a[r];   qb[r] = n1b[r] * n1b[r];
                s1[0][r] = n1a[r];         s1[1][r] = n1b[r];
            }
            // ring: k0..31 = n1 (pads 0), k32..63 = n1^2 (pads 0)
            unsigned char* rp = ring + (size_t)(t & (SLOTS - 1)) * SLOT_B + (size_t)j15 * ROWB;
            *(uint2*)(rp + 8 * g)      = make_uint2(pk2(n1a[0], n1a[1]), pk2(n1a[2], n1a[3]));
            *(uint2*)(rp + 32 + 8 * g) = make_uint2(pk2(n1b[0], n1b[1]), pk2(n1b[2], n1b[3]));
            *(uint2*)(rp + 64 + 8 * g) = make_uint2(pk2(qa[0], qa[1]), pk2(qa[2], qa[3]));
            *(uint2*)(rp + 96 + 8 * g) = make_uint2(pk2(qb[0], qb[1]), pk2(qb[2], qb[3]));
        };

        // initial: buffer A = steps 0..3, buffer B = steps 4..7
        float4 ca[4], cb4[4], na[4], nb[4];
        auto load4 = [&](float4* A, float4* Bv, int grp) {
            if (ld) {
                const float* q = sp + (size_t)grp * 64;
#pragma unroll
                for (int i = 0; i < 4; ++i) {
                    A[i] = *(const float4*)(q + 16 * i);
                    Bv[i] = *(const float4*)(q + 16 * i + 4);
                }
            }
        };
        load4(ca, cb4, 0);
        load4(na, nb, 1);

#pragma unroll 1
        for (int j = 0; j < 32; ++j) {           // 8 steps per barrier interval
#pragma unroll
            for (int i = 0; i < 4; ++i) pstep(8 * j + i, ca[i], cb4[i]);
            load4(ca, cb4, (2 * j + 2 < 64) ? 2 * j + 2 : 63);
#pragma unroll
            for (int i = 0; i < 4; ++i) pstep(8 * j + 4 + i, na[i], nb[i]);
            load4(na, nb, (2 * j + 3 < 64) ? 2 * j + 3 : 63);
            bar_sync();                          // 32 in-loop barriers
        }
        bar_sync();                              // balance consumer's initial
    } else {
        // ================= CONSUMER: layer 2 (s2 chain) =================
        // y-scratch: zeros + persistent k48 = 1.0 (folds br2 via A4 bias col)
        for (int i = lane; i < 16 * ROWB / 4; i += 64) ((unsigned*)tr1)[i] = 0u;
        if (lane < 16) *(unsigned short*)(tr1 + lane * ROWB + 96) = 0x3F80;

        // A3a[t<3] = gamma-folded W2^T over k(=n1)0..23; A3a[3]/A3b3 = sum rows
        bf16x8 A3a[4], A3b3, A4[3][2];
#pragma unroll
        for (int t = 0; t < 3; ++t) {
            const int m = 16 * t + j15;
            FragU f3, f4a, f4b;
#pragma unroll
            for (int j = 0; j < 8; ++j) {
                const int k = 8 * g + j;                 // 0..31
                const float v3 = (k < U1) ? g1[k] * W2[k * U2 + m] : 0.f;
                const int kb = 32 + k;                   // 32..63
                const float va = Wr2[k * U2 + m];
                const float vb = (kb < U2) ? Wr2[kb * U2 + m] : (kb == U2 ? br2[m] : 0.f);
                f3.v[j] = (short)f2bf(v3);
                f4a.v[j] = (short)f2bf(va);
                f4b.v[j] = (short)f2bf(vb);
            }
            A3a[t] = f3.v; A4[t][0] = f4a.v; A4[t][1] = f4b.v;
        }
        {   // tile3: rows 48+4q -> ones over n1 cols; rows 49+4q -> ones over n1^2 cols
            FragU fa, fb;
#pragma unroll
            for (int j = 0; j < 8; ++j) {
                const int k = 8 * g + j;
                fa.v[j] = ((j15 & 3) == 0 && k < U1) ? (short)0x3F80 : (short)0;
                fb.v[j] = ((j15 & 3) == 1 && k < U1) ? (short)0x3F80 : (short)0;
            }
            A3a[3] = fa.v; A3b3 = fb.v;
        }
        // per-lane LN-fold constants: c[m] = sum_k bf16(g1.W2), d[m] = b2 + W2^T.be1
        float cC[12], dC[12];
#pragma unroll
        for (int i = 0; i < 12; ++i) {
            const int m = 16 * (i >> 2) + 4 * g + (i & 3);
            float cc = 0.f, dd = b2[m];
            for (int k = 0; k < U1; ++k) {
                cc += bfr(g1[k] * W2[k * U2 + m]);       // match matmul quantization
                dd += be1[k] * W2[k * U2 + m];
            }
            cC[i] = cc; dC[i] = dd;
        }
        unsigned char* const yrow = tr1 + (size_t)j15 * ROWB;
        f32x4 s2[3] = {z4, z4, z4};

        auto cstep = [&](int t) {
            const unsigned char* sb = ring + (size_t)(t & (SLOTS - 1)) * SLOT_B;
            const bf16x8 hf0 = *(const bf16x8*)(sb + (size_t)j15 * ROWB + 16 * g);
            const bf16x8 hf1 = *(const bf16x8*)(sb + (size_t)j15 * ROWB + 64 + 16 * g);

            // sums first (gates rs), then P tiles
            f32x4 sAcc = MFMA(A3a[3], hf0, z4);
            sAcc = MFMA(A3b3, hf1, sAcc);                 // reg0 = Sum n1, reg1 = Sum n1^2
            const f32x4 P0 = MFMA(A3a[0], hf0, z4);
            const f32x4 P1 = MFMA(A3a[1], hf0, z4);
            const f32x4 P2 = MFMA(A3a[2], hf0, z4);

            const float mu = sAcc[0] * (1.f / U1);
            const float var = sAcc[1] * (1.f / U1) - mu * mu;
            const float rs = rsq_fast(var + 1e-3f);

            // y = rs*(P - mu*c) + (d + s2); first 8 written before 4 more computed
            float y[12];
#pragma unroll
            for (int r = 0; r < 4; ++r) {
                y[r]     = fmaf(rs, fmaf(-mu, cC[r],     P0[r]), dC[r]     + s2[0][r]);
                y[4 + r] = fmaf(rs, fmaf(-mu, cC[4 + r], P1[r]), dC[4 + r] + s2[1][r]);
            }
            *(uint2*)(yrow + 8 * g)      = make_uint2(pk2(y[0], y[1]), pk2(y[2], y[3]));
            *(uint2*)(yrow + 32 + 8 * g) = make_uint2(pk2(y[4], y[5]), pk2(y[6], y[7]));
            const bf16x8 yf0 = *(const bf16x8*)(yrow + 16 * g);
#pragma unroll
            for (int r = 0; r < 4; ++r)
                y[8 + r] = fmaf(rs, fmaf(-mu, cC[8 + r], P2[r]), dC[8 + r] + s2[2][r]);
            *(uint2*)(yrow + 64 + 8 * g) = make_uint2(pk2(y[8], y[9]), pk2(y[10], y[11]));
            const bf16x8 yf1 = *(const bf16x8*)(yrow + 64 + 16 * g);

            // GEMM4: s2 = tanh([Wr2^T|br2].y^T)
#pragma unroll
            for (int t3 = 0; t3 < 3; ++t3) {
                f32x4 e = MFMA(A4[t3][0], yf0, z4);
                e = MFMA(A4[t3][1], yf1, e);
#pragma unroll
                for (int r = 0; r < 4; ++r) s2[t3][r] = fast_tanh(e[r]);
            }
        };

        bar_sync();                                       // wait for producer interval 0
#pragma unroll 1
        for (int j = 0; j < 32; ++j) {
#pragma unroll
            for (int i = 0; i < 8; ++i) cstep(8 * j + i);
            bar_sync();                                   // 32 in-loop barriers
        }

        // ---- epilogue: out = sigmoid(LN(s2) @ Wout + bout) ----
        float g2r[12], be2r[12], wor[12];
#pragma unroll
        for (int r = 0; r < 12; ++r) {
            const int n = 16 * (r >> 2) + 4 * g + (r & 3);
            g2r[r] = g2[n]; be2r[r] = be2[n]; wor[r] = Wout[n];
        }
        float sm = 0.f, sq = 0.f;
#pragma unroll
        for (int tt = 0; tt < 3; ++tt)
#pragma unroll
            for (int r = 0; r < 4; ++r) { const float v = s2[tt][r]; sm += v; sq += v * v; }
        sm += __shfl_xor(sm, 16, 64); sq += __shfl_xor(sq, 16, 64);
        sm += __shfl_xor(sm, 32, 64); sq += __shfl_xor(sq, 32, 64);
        const float mu = sm * (1.f / U2);
        const float var = sq * (1.f / U2) - mu * mu;
        const float rs = rsq_fast(var + 1e-3f);
        float p = 0.f;
#pragma unroll
        for (int tt = 0; tt < 3; ++tt)
#pragma unroll
            for (int r = 0; r < 4; ++r)
                p += ((s2[tt][r] - mu) * rs * g2r[4 * tt + r] + be2r[4 * tt + r]) * wor[4 * tt + r];
        p += __shfl_xor(p, 16, 64);
        p += __shfl_xor(p, 32, 64);
        if (lane < 16) {
            const float z = p + bout[0];
            out[blockIdx.x * 16 + lane] = rcp_fast(1.0f + exp2_fast(-1.4426950408889634f * z));
        }
    }
}

extern "C" void kernel_launch(void* const* d_in, const int* in_sizes, int n_in,
                              void* d_out, int out_size, void* d_ws, size_t ws_size,
                              hipStream_t stream) {
    const float* seq  = (const float*)d_in[0];
    const float* W1   = (const float*)d_in[1];
    const float* b1   = (const float*)d_in[2];
    const float* Wr1  = (const float*)d_in[3];
    const float* br1  = (const float*)d_in[4];
    const float* g1   = (const float*)d_in[5];
    const float* be1  = (const float*)d_in[6];
    const float* W2   = (const float*)d_in[7];
    const float* b2   = (const float*)d_in[8];
    const float* Wr2  = (const float*)d_in[9];
    const float* br2  = (const float*)d_in[10];
    const float* g2   = (const float*)d_in[11];
    const float* be2  = (const float*)d_in[12];
    const float* Wout = (const float*)d_in[13];
    const float* bout = (const float*)d_in[14];
    float* out = (float*)d_out;

    const int B = in_sizes[0] / (T_STEPS * FEAT);   // 8192
    const int grid = B / 16;                        // 512 blocks x 2 waves
    rnn_kernel<<<grid, 128, 0, stream>>>(seq, W1, b1, Wr1, br1, g1, be1,
                                         W2, b2, Wr2, br2, g2, be2, Wout, bout, out);
}